// Round 12
// baseline (201.892 us; speedup 1.0000x reference)
//
#include <hip/hip_runtime.h>

// GCN 2-layer forward, N=100000, E=3200000, 128->16->2.
// Session-2 round-11 (prev 179.2us verified; fat-kernel overlap -9.1us,
// underdelivered vs -13..18 predicted -- suspect 52KB LDS union capping
// co-residency at 3 blocks/CU, below the 4-block wave cap).
// This round, two independent changes:
//  1. EPB 8192 -> 6144: fat LDS 52 -> 40KB (exactly 4 blocks/CU, wave cap).
//     Both roles gain 33% resident waves. 521 scatter blocks.
//  2. Degree-sorted perm: agg waves run 4 nodes in lockstep; trips = max of
//     4 Poisson(32) degrees (~18% lane waste). fillB counting-sorts each
//     256-node tile by degree (reusing free bs[] LDS) -> perm[]; agg uses
//     wid = perm[wid0]. Edge order per node untouched -> BIT-IDENTICAL.
// Validated and kept: fat scatter||xw1 fusion, deferred dinv scale in fillB
// tail, fixed-stride regions, register-staged scatter, uint4 fillB passes.
// LESSONS: hot-address global atomicAdd serializes; LDS-atomic aggregation
// 8x worse than sorted gather; gather-reduce at high occupancy wants many
// nodes/wave + shallow trees (r8); check Occupancy before "latency-bound".
// Algebra: hs = (x@W1)*dinv;
//   h1[d]  = relu(dinv[d]*(sum_nbr hs + hs[d]) + b1), W2 fused -> h2s
//   out[d] = dinv[d]*(sum_nbr h2s + h2s[d]) + b2

#define EPB  6144    // edges per partition block (40KB LDS -> 4 blocks/CU)
#define RCAP 12288   // per-bucket region capacity (mean 8192, sigma~90)
#define CAP  16384   // LDS slots per bucket in k_fillB

typedef unsigned int u32;
typedef unsigned short u16;

__device__ __forceinline__ float bflo(u32 u) { return __uint_as_float(u << 16); }
__device__ __forceinline__ float bfhi(u32 u) { return __uint_as_float(u & 0xffff0000u); }
__device__ __forceinline__ u32 pack_bf2(float a, float b) {   // RNE
    u32 ua = __float_as_uint(a); ua = (ua + 0x7fffu + ((ua >> 16) & 1u)) >> 16;
    u32 ub = __float_as_uint(b); ub = (ub + 0x7fffu + ((ub >> 16) & 1u)) >> 16;
    return ua | (ub << 16);
}

// ---------------- init bucket region cursors ----------------
__global__ __launch_bounds__(512) void k_binit(int* __restrict__ gcur, int NBUK) {
    int t = threadIdx.x;
    if (t < NBUK) gcur[t] = t * RCAP;
}

// ---------------- FAT: partition (blocks < NSCAT) || hraw = x@W1 (rest) -----
__global__ __launch_bounds__(512) void k_fat(const int* __restrict__ ei,
                                             int* __restrict__ gcur,
                                             u32* __restrict__ part,
                                             const float* __restrict__ x,
                                             const float* __restrict__ W1,
                                             float* __restrict__ hraw,
                                             int E, int NBUK, int NSCAT, int N) {
    __shared__ union {
        struct { int hist[512]; int rbase[512]; u32 buf[EPB]; u16 bkt[EPB]; } s;
        float w[4 * 516];   // xw1: section q = W1 rows 32q..32q+31; +4 pad
    } sm;
    int tid = threadIdx.x;
    if ((int)blockIdx.x < NSCAT) {
        // ---- scatter: count+scan+reserve+place, edges staged in registers --
        sm.s.hist[tid] = 0;
        __syncthreads();
        int base = blockIdx.x * EPB;
        int end = base + EPB; if (end > E) end = E;
        int cnt = end - base;
        int nv = cnt >> 2;
        const int4* s4p = (const int4*)(ei + base);
        const int4* d4p = (const int4*)(ei + E + base);
        int4 s4[3], d4[3];
        #pragma unroll
        for (int k = 0; k < 3; ++k) {
            int idx = tid + (k << 9);
            if (idx < nv) {
                s4[k] = s4p[idx];
                d4[k] = d4p[idx];
                atomicAdd(&sm.s.hist[d4[k].x >> 8], 1);
                atomicAdd(&sm.s.hist[d4[k].y >> 8], 1);
                atomicAdd(&sm.s.hist[d4[k].z >> 8], 1);
                atomicAdd(&sm.s.hist[d4[k].w >> 8], 1);
            }
        }
        for (int e = base + (nv << 2) + tid; e < end; e += 512)  // tail
            atomicAdd(&sm.s.hist[ei[E + e] >> 8], 1);
        __syncthreads();
        int v = sm.s.hist[tid];
        __syncthreads();
        for (int o = 1; o < 512; o <<= 1) {                      // in-place scan
            int t = (tid >= o) ? sm.s.hist[tid - o] : 0;
            __syncthreads();
            sm.s.hist[tid] += t;
            __syncthreads();
        }
        int excl = sm.s.hist[tid] - v;
        int rb = 0;
        if (tid < NBUK && v > 0) rb = atomicAdd(&gcur[tid], v);  // reserve run
        sm.s.rbase[tid] = rb - excl;
        __syncthreads();
        sm.s.hist[tid] = excl;        // placement cursor (own slot only)
        __syncthreads();
        #pragma unroll
        for (int k = 0; k < 3; ++k) {
            int idx = tid + (k << 9);
            if (idx < nv) {
                int b, pos;
                b = d4[k].x >> 8; pos = atomicAdd(&sm.s.hist[b], 1);
                sm.s.buf[pos] = ((u32)(d4[k].x & 255) << 24) | (u32)s4[k].x; sm.s.bkt[pos] = (u16)b;
                b = d4[k].y >> 8; pos = atomicAdd(&sm.s.hist[b], 1);
                sm.s.buf[pos] = ((u32)(d4[k].y & 255) << 24) | (u32)s4[k].y; sm.s.bkt[pos] = (u16)b;
                b = d4[k].z >> 8; pos = atomicAdd(&sm.s.hist[b], 1);
                sm.s.buf[pos] = ((u32)(d4[k].z & 255) << 24) | (u32)s4[k].z; sm.s.bkt[pos] = (u16)b;
                b = d4[k].w >> 8; pos = atomicAdd(&sm.s.hist[b], 1);
                sm.s.buf[pos] = ((u32)(d4[k].w & 255) << 24) | (u32)s4[k].w; sm.s.bkt[pos] = (u16)b;
            }
        }
        for (int e = base + (nv << 2) + tid; e < end; e += 512) { // tail re-read
            int s = ei[e], d = ei[E + e];
            int b = d >> 8;
            int pos = atomicAdd(&sm.s.hist[b], 1);
            sm.s.buf[pos] = ((u32)(d & 255) << 24) | (u32)s;
            sm.s.bkt[pos] = (u16)b;
        }
        __syncthreads();
        for (int j = tid; j < cnt; j += 512)
            part[sm.s.rbase[sm.s.bkt[j]] + j] = sm.s.buf[j];     // ~coalesced
    } else {
        // ---- xw1_raw: hraw[n][16] = x[n]@W1 (f32, no dinv), K-split x4 -----
        for (int t = tid; t < 2048; t += 512)
            sm.w[(t >> 9) * 516 + (t & 511)] = W1[t];
        __syncthreads();
        int t = ((int)blockIdx.x - NSCAT) * 512 + tid;
        int n = t >> 2, q = t & 3;
        if (n >= N) return;
        const float4* xr = (const float4*)(x + (size_t)n * 128 + q * 32);  // 8 f4
        const float* ws = sm.w + q * 516;
        float acc[16];
        #pragma unroll
        for (int c = 0; c < 16; ++c) acc[c] = 0.f;
        #pragma unroll
        for (int i = 0; i < 8; ++i) {
            float4 u = xr[i];
            const float4* wf = (const float4*)(ws + i * 64);  // rows 4i..4i+3
            #pragma unroll
            for (int c4 = 0; c4 < 4; ++c4) {
                float4 wa = wf[c4];
                float4 wb = wf[4 + c4];
                float4 wc = wf[8 + c4];
                float4 wd = wf[12 + c4];
                int c = c4 * 4;
                acc[c+0] = fmaf(u.x, wa.x, acc[c+0]); acc[c+1] = fmaf(u.x, wa.y, acc[c+1]);
                acc[c+2] = fmaf(u.x, wa.z, acc[c+2]); acc[c+3] = fmaf(u.x, wa.w, acc[c+3]);
                acc[c+0] = fmaf(u.y, wb.x, acc[c+0]); acc[c+1] = fmaf(u.y, wb.y, acc[c+1]);
                acc[c+2] = fmaf(u.y, wb.z, acc[c+2]); acc[c+3] = fmaf(u.y, wb.w, acc[c+3]);
                acc[c+0] = fmaf(u.z, wc.x, acc[c+0]); acc[c+1] = fmaf(u.z, wc.y, acc[c+1]);
                acc[c+2] = fmaf(u.z, wc.z, acc[c+2]); acc[c+3] = fmaf(u.z, wc.w, acc[c+3]);
                acc[c+0] = fmaf(u.w, wd.x, acc[c+0]); acc[c+1] = fmaf(u.w, wd.y, acc[c+1]);
                acc[c+2] = fmaf(u.w, wd.z, acc[c+2]); acc[c+3] = fmaf(u.w, wd.w, acc[c+3]);
            }
        }
        #pragma unroll
        for (int c = 0; c < 16; ++c) {
            acc[c] += __shfl_xor(acc[c], 1);
            acc[c] += __shfl_xor(acc[c], 2);
        }
        ((float4*)(hraw + (size_t)n * 16))[q] =
            make_float4(acc[4*q+0], acc[4*q+1], acc[4*q+2], acc[4*q+3]);
    }
}

// ---------------- per-bucket sort by dst; region -> dense csr ---------------
// In-kernel bucket scan; uint4 passes; tail: hs = hraw*dinv + degree perm.
__global__ __launch_bounds__(512) void k_fillB(const u32* __restrict__ part,
                                               const int* __restrict__ gcur,
                                               u32* __restrict__ csr,
                                               int* __restrict__ rp,
                                               float* __restrict__ dinv,
                                               const float* __restrict__ hraw,
                                               u16* __restrict__ hs,
                                               int* __restrict__ perm,
                                               int N, int E, int NBUK) {
    __shared__ int hist[256];
    __shared__ int ofs[256];
    __shared__ int bs[512];      // bucket-count scan; later degree-sort scratch
    __shared__ u32 srcbuf[CAP];
    int b = blockIdx.x, tid = threadIdx.x;
    if (b == 0 && tid == 0) rp[N] = E;
    int vb = (tid < NBUK) ? (gcur[tid] - tid * RCAP) : 0;
    bs[tid] = vb;
    if (tid < 256) hist[tid] = 0;
    __syncthreads();
    for (int o = 1; o < 512; o <<= 1) {
        int t = (tid >= o) ? bs[tid - o] : 0;
        __syncthreads();
        bs[tid] += t;
        __syncthreads();
    }
    int cnt = gcur[b] - b * RCAP;
    int base_w = bs[b] - cnt;              // dense write base
    int base_r = b * RCAP;                 // region read base (16B aligned)
    int nv = cnt >> 2;
    const uint4* p4 = (const uint4*)(part + base_r);
    for (int t = tid; t < nv; t += 512) {
        uint4 pv = p4[t];
        atomicAdd(&hist[pv.x >> 24], 1);
        atomicAdd(&hist[pv.y >> 24], 1);
        atomicAdd(&hist[pv.z >> 24], 1);
        atomicAdd(&hist[pv.w >> 24], 1);
    }
    for (int j = (nv << 2) + tid; j < cnt; j += 512)
        atomicAdd(&hist[part[base_r + j] >> 24], 1);
    __syncthreads();
    int v = 0;
    if (tid < 256) { v = hist[tid]; ofs[tid] = v; }
    __syncthreads();
    for (int o = 1; o < 256; o <<= 1) {
        int t = 0;
        if (tid < 256 && tid >= o) t = ofs[tid - o];
        __syncthreads();
        if (tid < 256) ofs[tid] += t;
        __syncthreads();
    }
    int excl = 0;
    if (tid < 256) { excl = ofs[tid] - v; hist[tid] = excl; }
    __syncthreads();
    for (int t = tid; t < nv; t += 512) {
        uint4 pv = p4[t];
        int pos;
        pos = atomicAdd(&hist[pv.x >> 24], 1);
        if (pos < CAP) srcbuf[pos] = pv.x & 0xFFFFFFu;
        pos = atomicAdd(&hist[pv.y >> 24], 1);
        if (pos < CAP) srcbuf[pos] = pv.y & 0xFFFFFFu;
        pos = atomicAdd(&hist[pv.z >> 24], 1);
        if (pos < CAP) srcbuf[pos] = pv.z & 0xFFFFFFu;
        pos = atomicAdd(&hist[pv.w >> 24], 1);
        if (pos < CAP) srcbuf[pos] = pv.w & 0xFFFFFFu;
    }
    for (int j = (nv << 2) + tid; j < cnt; j += 512) {
        u32 pv = part[base_r + j];
        int pos = atomicAdd(&hist[pv >> 24], 1);
        if (pos < CAP) srcbuf[pos] = pv & 0xFFFFFFu;
    }
    __syncthreads();
    for (int j = tid; j < cnt; j += 512)
        csr[base_w + j] = srcbuf[j];       // coalesced dense write
    int d = b * 256 + tid;
    if (tid < 256 && d < N) {
        rp[d] = base_w + excl;
        float dval = rsqrtf((float)(v + 1));   // +1 self loop
        dinv[d] = dval;
        ((float*)ofs)[tid] = dval;             // stash for scale step
    }
    __syncthreads();
    // ---- hs[dn] = bf16(hraw[dn] * dinv[dn]); 2 threads/node, 16B halves ----
    int dn = b * 256 + (tid >> 1);
    if (dn < N) {
        float di = ((float*)ofs)[tid >> 1];
        int h = tid & 1;
        const float4* hr = (const float4*)(hraw + (size_t)dn * 16);
        float4 A = hr[h * 2], B = hr[h * 2 + 1];
        uint4 o;
        o.x = pack_bf2(A.x * di, A.y * di);
        o.y = pack_bf2(A.z * di, A.w * di);
        o.z = pack_bf2(B.x * di, B.y * di);
        o.w = pack_bf2(B.z * di, B.w * di);
        ((uint4*)(hs + (size_t)dn * 16))[h] = o;
    }
    // ---- degree counting-sort of this 256-node tile -> perm ----
    __syncthreads();                 // bs free (base_w consumed long ago)
    if (tid < 256) bs[tid] = 0;      // [0..127] deg counts, [128..255] cursors
    __syncthreads();
    bool valid = (tid < 256) && (d < N);
    int dg = 0;
    if (valid) { dg = v > 127 ? 127 : v; atomicAdd(&bs[dg], 1); }
    __syncthreads();
    for (int o = 1; o < 128; o <<= 1) {  // inclusive scan of bs[0..127]
        int t = 0;
        if (tid < 128 && tid >= o) t = bs[tid - o];
        __syncthreads();
        if (tid < 128) bs[tid] += t;
        __syncthreads();
    }
    if (valid) {
        int rank0 = dg ? bs[dg - 1] : 0;            // exclusive base
        int r = atomicAdd(&bs[128 + dg], 1);
        perm[b * 256 + rank0 + r] = d;              // tile-local degree order
    }
}

// ---------------- fused layer-1 gather + ReLU + W2 projection ----------------
// 4 nodes/wave (degree-matched via perm); 2 halves x 8 edge groups.
__global__ __launch_bounds__(256) void k_agg1h2(const int* __restrict__ rp,
                                                const int* __restrict__ csr,
                                                const u16* __restrict__ hs,
                                                const float* __restrict__ dinv,
                                                const float* __restrict__ W2,
                                                const float* __restrict__ b1,
                                                const int* __restrict__ perm,
                                                float* __restrict__ h2s, int N) {
    int lane = threadIdx.x & 63;
    int wid0 = blockIdx.x * 16 + (threadIdx.x >> 6) * 4 + (lane >> 4);
    if (wid0 >= N) return;
    int wid = perm[wid0];
    int l = lane & 15;
    int half = l & 1, g = l >> 1;                  // 16B half, edge group
    int beg = rp[wid], end = rp[wid + 1];
    float a0 = 0.f, a1 = 0.f, a2 = 0.f, a3 = 0.f;
    float a4 = 0.f, a5 = 0.f, a6 = 0.f, a7 = 0.f;
    for (int j = beg + g; j < end; j += 8) {
        int s = csr[j];
        uint4 u = ((const uint4*)(hs + (size_t)s * 16))[half];
        a0 += bflo(u.x); a1 += bfhi(u.x);
        a2 += bflo(u.y); a3 += bfhi(u.y);
        a4 += bflo(u.z); a5 += bfhi(u.z);
        a6 += bflo(u.w); a7 += bfhi(u.w);
    }
    a0 += __shfl_xor(a0, 2); a1 += __shfl_xor(a1, 2);
    a2 += __shfl_xor(a2, 2); a3 += __shfl_xor(a3, 2);
    a4 += __shfl_xor(a4, 2); a5 += __shfl_xor(a5, 2);
    a6 += __shfl_xor(a6, 2); a7 += __shfl_xor(a7, 2);
    a0 += __shfl_xor(a0, 4); a1 += __shfl_xor(a1, 4);
    a2 += __shfl_xor(a2, 4); a3 += __shfl_xor(a3, 4);
    a4 += __shfl_xor(a4, 4); a5 += __shfl_xor(a5, 4);
    a6 += __shfl_xor(a6, 4); a7 += __shfl_xor(a7, 4);
    a0 += __shfl_xor(a0, 8); a1 += __shfl_xor(a1, 8);
    a2 += __shfl_xor(a2, 8); a3 += __shfl_xor(a3, 8);
    a4 += __shfl_xor(a4, 8); a5 += __shfl_xor(a5, 8);
    a6 += __shfl_xor(a6, 8); a7 += __shfl_xor(a7, 8);
    uint4 su = ((const uint4*)(hs + (size_t)wid * 16))[half];   // self term
    a0 += bflo(su.x); a1 += bfhi(su.x);
    a2 += bflo(su.y); a3 += bfhi(su.y);
    a4 += bflo(su.z); a5 += bfhi(su.z);
    a6 += bflo(su.w); a7 += bfhi(su.w);
    float di = dinv[wid];
    float4 bA = ((const float4*)b1)[half * 2];
    float4 bB = ((const float4*)b1)[half * 2 + 1];
    float v0 = fmaxf(fmaf(di, a0, bA.x), 0.f);
    float v1 = fmaxf(fmaf(di, a1, bA.y), 0.f);
    float v2 = fmaxf(fmaf(di, a2, bA.z), 0.f);
    float v3 = fmaxf(fmaf(di, a3, bA.w), 0.f);
    float v4 = fmaxf(fmaf(di, a4, bB.x), 0.f);
    float v5 = fmaxf(fmaf(di, a5, bB.y), 0.f);
    float v6 = fmaxf(fmaf(di, a6, bB.z), 0.f);
    float v7 = fmaxf(fmaf(di, a7, bB.w), 0.f);
    const float4* w4 = (const float4*)W2 + half * 4;   // rows half*8..+7
    float4 q0 = w4[0], q1 = w4[1], q2 = w4[2], q3 = w4[3];
    float p0 = v0*q0.x + v1*q0.z + v2*q1.x + v3*q1.z
             + v4*q2.x + v5*q2.z + v6*q3.x + v7*q3.z;
    float p1 = v0*q0.y + v1*q0.w + v2*q1.y + v3*q1.w
             + v4*q2.y + v5*q2.w + v6*q3.y + v7*q3.w;
    p0 += __shfl_xor(p0, 1); p1 += __shfl_xor(p1, 1);  // sum the two halves
    if (l == 0)
        *(float2*)(h2s + (size_t)wid * 2) = make_float2(p0 * di, p1 * di);
}

// ---------------- layer-2 gather -> out (4 nodes/wave, degree-matched) ------
__global__ __launch_bounds__(256) void k_agg2(const int* __restrict__ rp,
                                              const int* __restrict__ csr,
                                              const float* __restrict__ h2s,
                                              const float* __restrict__ dinv,
                                              const float* __restrict__ b2,
                                              const int* __restrict__ perm,
                                              float* __restrict__ out, int N) {
    int lane = threadIdx.x & 63;
    int wid0 = blockIdx.x * 16 + (threadIdx.x >> 6) * 4 + (lane >> 4);
    if (wid0 >= N) return;
    int wid = perm[wid0];
    int l = lane & 15;
    int beg = rp[wid], end = rp[wid + 1];
    float a0 = 0.f, a1 = 0.f;
    for (int j = beg + l; j < end; j += 16) {
        int s = csr[j];
        float2 v = *(const float2*)(h2s + (size_t)s * 2);
        a0 += v.x; a1 += v.y;
    }
    a0 += __shfl_xor(a0, 1); a1 += __shfl_xor(a1, 1);
    a0 += __shfl_xor(a0, 2); a1 += __shfl_xor(a1, 2);
    a0 += __shfl_xor(a0, 4); a1 += __shfl_xor(a1, 4);
    a0 += __shfl_xor(a0, 8); a1 += __shfl_xor(a1, 8);
    if (l == 0) {
        float di = dinv[wid];
        float2 sv = *(const float2*)(h2s + (size_t)wid * 2);
        *(float2*)(out + (size_t)wid * 2) =
            make_float2(fmaf(di, a0 + sv.x, b2[0]), fmaf(di, a1 + sv.y, b2[1]));
    }
}

extern "C" void kernel_launch(void* const* d_in, const int* in_sizes, int n_in,
                              void* d_out, int out_size, void* d_ws, size_t ws_size,
                              hipStream_t stream) {
    const float* x  = (const float*)d_in[0];
    const int*   ei = (const int*)d_in[1];
    const float* W1 = (const float*)d_in[2];
    const float* b1 = (const float*)d_in[3];
    const float* W2 = (const float*)d_in[4];
    const float* b2 = (const float*)d_in[5];
    float* out = (float*)d_out;

    const int N = in_sizes[0] / 128;      // 100000
    const int E = in_sizes[1] / 2;        // 3200000
    const int NBUK = (N + 255) / 256;     // 391 (<= 512)
    const int NPB  = (E + EPB - 1) / EPB; // 521 (scatter blocks)
    const int NXW  = (N * 4 + 511) / 512; // 782 (xw1 blocks)

    char* ws = (char*)d_ws;
    size_t off = 0;
    auto alloc = [&](size_t bytes) {
        void* p = ws + off;
        off = (off + bytes + 255) & ~(size_t)255;
        return p;
    };
    u32*   part  = (u32*)alloc((size_t)NBUK * RCAP * 4); // strided regions
    u32*   csr   = (u32*)alloc((size_t)E * 4);           // dense sorted
    int*   rp    = (int*)alloc((size_t)(N + 1) * 4);
    float* dinv  = (float*)alloc((size_t)N * 4);
    float* hraw  = (float*)alloc((size_t)N * 16 * 4);    // f32 x@W1, no dinv
    u16*   hs    = (u16*)alloc((size_t)N * 16 * 2);      // bf16 scaled
    float* h2s   = (float*)alloc((size_t)N * 2 * 4);
    int*   perm  = (int*)alloc((size_t)N * 4);           // degree-sorted ids
    int*   gcur  = (int*)alloc((size_t)NBUK * 4);

    k_binit  <<<dim3(1),          dim3(512), 0, stream>>>(gcur, NBUK);
    k_fat    <<<dim3(NPB + NXW),  dim3(512), 0, stream>>>(ei, gcur, part, x, W1, hraw, E, NBUK, NPB, N);
    k_fillB  <<<dim3(NBUK),       dim3(512), 0, stream>>>(part, gcur, csr, rp, dinv, hraw, hs, perm, N, E, NBUK);
    k_agg1h2 <<<dim3((N + 15) / 16), dim3(256), 0, stream>>>(rp, (const int*)csr, hs, dinv, W2, b1, perm, h2s, N);
    k_agg2   <<<dim3((N + 15) / 16), dim3(256), 0, stream>>>(rp, (const int*)csr, h2s, dinv, b2, perm, out, N);
}

// Round 14
// 181.842 us; speedup vs baseline: 1.1103x; 1.1103x over previous
//
#include <hip/hip_runtime.h>

// GCN 2-layer forward, N=100000, E=3200000, 128->16->2.
// Session-2 round-13: verbatim resubmit of round-12 source (round-13 bench
// was an infra failure: GPUAcquisitionTimeout -- code never ran).
// Round-12 content under test: REVERT of r11's two regressions
// (179.2->201.9: EPB 6144 made fat slower w/ Occ 37-43% despite LDS
// headroom -> occupancy never the limiter; degree-perm +17us in agg --
// adjacent-wid contiguity was load-bearing. LESSON: anti-divergence
// reordering must reorder the DATA, not just the wave->node map).
// Plus one isolated change: k_binit replaced by hipMemsetAsync(gcur,0),
// gcur[b] = pure count (reserve = b*RCAP + atomicAdd); -1 launch.
// Validated and kept: fat scatter||xw1 fusion (-9.1us), deferred dinv scale
// in fillB tail, fixed-stride regions (EPB 8192), register-staged scatter,
// uint4 fillB passes, 4-nodes/wave agg.
// LESSONS: hot-address global atomicAdd serializes; LDS-atomic aggregation
// 8x worse than sorted gather; many nodes/wave + shallow trees for
// gather-reduce (r8); measure Occupancy before tuning for it (r11/r12).
// Algebra: hs = (x@W1)*dinv;
//   h1[d]  = relu(dinv[d]*(sum_nbr hs + hs[d]) + b1), W2 fused -> h2s
//   out[d] = dinv[d]*(sum_nbr h2s + h2s[d]) + b2

#define EPB  8192    // edges per partition block
#define RCAP 12288   // per-bucket region capacity (mean 8192, sigma~90)
#define CAP  16384   // LDS slots per bucket in k_fillB

typedef unsigned int u32;
typedef unsigned short u16;

__device__ __forceinline__ float bflo(u32 u) { return __uint_as_float(u << 16); }
__device__ __forceinline__ float bfhi(u32 u) { return __uint_as_float(u & 0xffff0000u); }
__device__ __forceinline__ u32 pack_bf2(float a, float b) {   // RNE
    u32 ua = __float_as_uint(a); ua = (ua + 0x7fffu + ((ua >> 16) & 1u)) >> 16;
    u32 ub = __float_as_uint(b); ub = (ub + 0x7fffu + ((ub >> 16) & 1u)) >> 16;
    return ua | (ub << 16);
}

// ---------------- FAT: partition (blocks < NSCAT) || hraw = x@W1 (rest) -----
__global__ __launch_bounds__(512) void k_fat(const int* __restrict__ ei,
                                             int* __restrict__ gcur,
                                             u32* __restrict__ part,
                                             const float* __restrict__ x,
                                             const float* __restrict__ W1,
                                             float* __restrict__ hraw,
                                             int E, int NBUK, int NSCAT, int N) {
    __shared__ union {
        struct { int hist[512]; int rbase[512]; u32 buf[EPB]; u16 bkt[EPB]; } s;
        float w[4 * 516];   // xw1: section q = W1 rows 32q..32q+31; +4 pad
    } sm;
    int tid = threadIdx.x;
    if ((int)blockIdx.x < NSCAT) {
        // ---- scatter: count+scan+reserve+place, edges staged in registers --
        sm.s.hist[tid] = 0;
        __syncthreads();
        int base = blockIdx.x * EPB;
        int end = base + EPB; if (end > E) end = E;
        int cnt = end - base;
        int nv = cnt >> 2;
        const int4* s4p = (const int4*)(ei + base);
        const int4* d4p = (const int4*)(ei + E + base);
        int4 s4[4], d4[4];
        #pragma unroll
        for (int k = 0; k < 4; ++k) {
            int idx = tid + (k << 9);
            if (idx < nv) {
                s4[k] = s4p[idx];
                d4[k] = d4p[idx];
                atomicAdd(&sm.s.hist[d4[k].x >> 8], 1);
                atomicAdd(&sm.s.hist[d4[k].y >> 8], 1);
                atomicAdd(&sm.s.hist[d4[k].z >> 8], 1);
                atomicAdd(&sm.s.hist[d4[k].w >> 8], 1);
            }
        }
        for (int e = base + (nv << 2) + tid; e < end; e += 512)  // tail
            atomicAdd(&sm.s.hist[ei[E + e] >> 8], 1);
        __syncthreads();
        int v = sm.s.hist[tid];
        __syncthreads();
        for (int o = 1; o < 512; o <<= 1) {                      // in-place scan
            int t = (tid >= o) ? sm.s.hist[tid - o] : 0;
            __syncthreads();
            sm.s.hist[tid] += t;
            __syncthreads();
        }
        int excl = sm.s.hist[tid] - v;
        int rb = 0;
        if (tid < NBUK && v > 0)                                 // reserve run
            rb = tid * RCAP + atomicAdd(&gcur[tid], v);
        sm.s.rbase[tid] = rb - excl;
        __syncthreads();
        sm.s.hist[tid] = excl;        // placement cursor (own slot only)
        __syncthreads();
        #pragma unroll
        for (int k = 0; k < 4; ++k) {
            int idx = tid + (k << 9);
            if (idx < nv) {
                int b, pos;
                b = d4[k].x >> 8; pos = atomicAdd(&sm.s.hist[b], 1);
                sm.s.buf[pos] = ((u32)(d4[k].x & 255) << 24) | (u32)s4[k].x; sm.s.bkt[pos] = (u16)b;
                b = d4[k].y >> 8; pos = atomicAdd(&sm.s.hist[b], 1);
                sm.s.buf[pos] = ((u32)(d4[k].y & 255) << 24) | (u32)s4[k].y; sm.s.bkt[pos] = (u16)b;
                b = d4[k].z >> 8; pos = atomicAdd(&sm.s.hist[b], 1);
                sm.s.buf[pos] = ((u32)(d4[k].z & 255) << 24) | (u32)s4[k].z; sm.s.bkt[pos] = (u16)b;
                b = d4[k].w >> 8; pos = atomicAdd(&sm.s.hist[b], 1);
                sm.s.buf[pos] = ((u32)(d4[k].w & 255) << 24) | (u32)s4[k].w; sm.s.bkt[pos] = (u16)b;
            }
        }
        for (int e = base + (nv << 2) + tid; e < end; e += 512) { // tail re-read
            int s = ei[e], d = ei[E + e];
            int b = d >> 8;
            int pos = atomicAdd(&sm.s.hist[b], 1);
            sm.s.buf[pos] = ((u32)(d & 255) << 24) | (u32)s;
            sm.s.bkt[pos] = (u16)b;
        }
        __syncthreads();
        for (int j = tid; j < cnt; j += 512)
            part[sm.s.rbase[sm.s.bkt[j]] + j] = sm.s.buf[j];     // ~coalesced
    } else {
        // ---- xw1_raw: hraw[n][16] = x[n]@W1 (f32, no dinv), K-split x4 -----
        for (int t = tid; t < 2048; t += 512)
            sm.w[(t >> 9) * 516 + (t & 511)] = W1[t];
        __syncthreads();
        int t = ((int)blockIdx.x - NSCAT) * 512 + tid;
        int n = t >> 2, q = t & 3;
        if (n >= N) return;
        const float4* xr = (const float4*)(x + (size_t)n * 128 + q * 32);  // 8 f4
        const float* ws = sm.w + q * 516;
        float acc[16];
        #pragma unroll
        for (int c = 0; c < 16; ++c) acc[c] = 0.f;
        #pragma unroll
        for (int i = 0; i < 8; ++i) {
            float4 u = xr[i];
            const float4* wf = (const float4*)(ws + i * 64);  // rows 4i..4i+3
            #pragma unroll
            for (int c4 = 0; c4 < 4; ++c4) {
                float4 wa = wf[c4];
                float4 wb = wf[4 + c4];
                float4 wc = wf[8 + c4];
                float4 wd = wf[12 + c4];
                int c = c4 * 4;
                acc[c+0] = fmaf(u.x, wa.x, acc[c+0]); acc[c+1] = fmaf(u.x, wa.y, acc[c+1]);
                acc[c+2] = fmaf(u.x, wa.z, acc[c+2]); acc[c+3] = fmaf(u.x, wa.w, acc[c+3]);
                acc[c+0] = fmaf(u.y, wb.x, acc[c+0]); acc[c+1] = fmaf(u.y, wb.y, acc[c+1]);
                acc[c+2] = fmaf(u.y, wb.z, acc[c+2]); acc[c+3] = fmaf(u.y, wb.w, acc[c+3]);
                acc[c+0] = fmaf(u.z, wc.x, acc[c+0]); acc[c+1] = fmaf(u.z, wc.y, acc[c+1]);
                acc[c+2] = fmaf(u.z, wc.z, acc[c+2]); acc[c+3] = fmaf(u.z, wc.w, acc[c+3]);
                acc[c+0] = fmaf(u.w, wd.x, acc[c+0]); acc[c+1] = fmaf(u.w, wd.y, acc[c+1]);
                acc[c+2] = fmaf(u.w, wd.z, acc[c+2]); acc[c+3] = fmaf(u.w, wd.w, acc[c+3]);
            }
        }
        #pragma unroll
        for (int c = 0; c < 16; ++c) {
            acc[c] += __shfl_xor(acc[c], 1);
            acc[c] += __shfl_xor(acc[c], 2);
        }
        ((float4*)(hraw + (size_t)n * 16))[q] =
            make_float4(acc[4*q+0], acc[4*q+1], acc[4*q+2], acc[4*q+3]);
    }
}

// ---------------- per-bucket sort by dst; region -> dense csr ---------------
// In-kernel bucket scan; uint4 passes; tail: hs = hraw*dinv (bf16 pack).
__global__ __launch_bounds__(512) void k_fillB(const u32* __restrict__ part,
                                               const int* __restrict__ gcur,
                                               u32* __restrict__ csr,
                                               int* __restrict__ rp,
                                               float* __restrict__ dinv,
                                               const float* __restrict__ hraw,
                                               u16* __restrict__ hs,
                                               int N, int E, int NBUK) {
    __shared__ int hist[256];
    __shared__ int ofs[256];
    __shared__ int bs[512];      // bucket-count scan
    __shared__ u32 srcbuf[CAP];
    int b = blockIdx.x, tid = threadIdx.x;
    if (b == 0 && tid == 0) rp[N] = E;
    int vb = (tid < NBUK) ? gcur[tid] : 0;         // gcur = pure counts now
    bs[tid] = vb;
    if (tid < 256) hist[tid] = 0;
    __syncthreads();
    for (int o = 1; o < 512; o <<= 1) {
        int t = (tid >= o) ? bs[tid - o] : 0;
        __syncthreads();
        bs[tid] += t;
        __syncthreads();
    }
    int cnt = gcur[b];
    int base_w = bs[b] - cnt;              // dense write base
    int base_r = b * RCAP;                 // region read base (16B aligned)
    int nv = cnt >> 2;
    const uint4* p4 = (const uint4*)(part + base_r);
    for (int t = tid; t < nv; t += 512) {
        uint4 pv = p4[t];
        atomicAdd(&hist[pv.x >> 24], 1);
        atomicAdd(&hist[pv.y >> 24], 1);
        atomicAdd(&hist[pv.z >> 24], 1);
        atomicAdd(&hist[pv.w >> 24], 1);
    }
    for (int j = (nv << 2) + tid; j < cnt; j += 512)
        atomicAdd(&hist[part[base_r + j] >> 24], 1);
    __syncthreads();
    int v = 0;
    if (tid < 256) { v = hist[tid]; ofs[tid] = v; }
    __syncthreads();
    for (int o = 1; o < 256; o <<= 1) {
        int t = 0;
        if (tid < 256 && tid >= o) t = ofs[tid - o];
        __syncthreads();
        if (tid < 256) ofs[tid] += t;
        __syncthreads();
    }
    int excl = 0;
    if (tid < 256) { excl = ofs[tid] - v; hist[tid] = excl; }
    __syncthreads();
    for (int t = tid; t < nv; t += 512) {
        uint4 pv = p4[t];
        int pos;
        pos = atomicAdd(&hist[pv.x >> 24], 1);
        if (pos < CAP) srcbuf[pos] = pv.x & 0xFFFFFFu;
        pos = atomicAdd(&hist[pv.y >> 24], 1);
        if (pos < CAP) srcbuf[pos] = pv.y & 0xFFFFFFu;
        pos = atomicAdd(&hist[pv.z >> 24], 1);
        if (pos < CAP) srcbuf[pos] = pv.z & 0xFFFFFFu;
        pos = atomicAdd(&hist[pv.w >> 24], 1);
        if (pos < CAP) srcbuf[pos] = pv.w & 0xFFFFFFu;
    }
    for (int j = (nv << 2) + tid; j < cnt; j += 512) {
        u32 pv = part[base_r + j];
        int pos = atomicAdd(&hist[pv >> 24], 1);
        if (pos < CAP) srcbuf[pos] = pv & 0xFFFFFFu;
    }
    __syncthreads();
    for (int j = tid; j < cnt; j += 512)
        csr[base_w + j] = srcbuf[j];       // coalesced dense write
    int d = b * 256 + tid;
    if (tid < 256 && d < N) {
        rp[d] = base_w + excl;
        float dval = rsqrtf((float)(v + 1));   // +1 self loop
        dinv[d] = dval;
        ((float*)ofs)[tid] = dval;             // stash for scale step
    }
    __syncthreads();
    // ---- hs[dn] = bf16(hraw[dn] * dinv[dn]); 2 threads/node, 16B halves ----
    int dn = b * 256 + (tid >> 1);
    if (dn < N) {
        float di = ((float*)ofs)[tid >> 1];
        int h = tid & 1;
        const float4* hr = (const float4*)(hraw + (size_t)dn * 16);
        float4 A = hr[h * 2], B = hr[h * 2 + 1];
        uint4 o;
        o.x = pack_bf2(A.x * di, A.y * di);
        o.y = pack_bf2(A.z * di, A.w * di);
        o.z = pack_bf2(B.x * di, B.y * di);
        o.w = pack_bf2(B.z * di, B.w * di);
        ((uint4*)(hs + (size_t)dn * 16))[h] = o;
    }
}

// ---------------- fused layer-1 gather + ReLU + W2 projection ----------------
// 4 nodes/wave; 16 lanes/node = 2 halves (16B uint4 each) x 8 edge groups.
__global__ __launch_bounds__(256) void k_agg1h2(const int* __restrict__ rp,
                                                const int* __restrict__ csr,
                                                const u16* __restrict__ hs,
                                                const float* __restrict__ dinv,
                                                const float* __restrict__ W2,
                                                const float* __restrict__ b1,
                                                float* __restrict__ h2s, int N) {
    int lane = threadIdx.x & 63;
    int wid = blockIdx.x * 16 + (threadIdx.x >> 6) * 4 + (lane >> 4);
    if (wid >= N) return;
    int l = lane & 15;
    int half = l & 1, g = l >> 1;                  // 16B half, edge group
    int beg = rp[wid], end = rp[wid + 1];
    float a0 = 0.f, a1 = 0.f, a2 = 0.f, a3 = 0.f;
    float a4 = 0.f, a5 = 0.f, a6 = 0.f, a7 = 0.f;
    for (int j = beg + g; j < end; j += 8) {
        int s = csr[j];
        uint4 u = ((const uint4*)(hs + (size_t)s * 16))[half];
        a0 += bflo(u.x); a1 += bfhi(u.x);
        a2 += bflo(u.y); a3 += bfhi(u.y);
        a4 += bflo(u.z); a5 += bfhi(u.z);
        a6 += bflo(u.w); a7 += bfhi(u.w);
    }
    a0 += __shfl_xor(a0, 2); a1 += __shfl_xor(a1, 2);
    a2 += __shfl_xor(a2, 2); a3 += __shfl_xor(a3, 2);
    a4 += __shfl_xor(a4, 2); a5 += __shfl_xor(a5, 2);
    a6 += __shfl_xor(a6, 2); a7 += __shfl_xor(a7, 2);
    a0 += __shfl_xor(a0, 4); a1 += __shfl_xor(a1, 4);
    a2 += __shfl_xor(a2, 4); a3 += __shfl_xor(a3, 4);
    a4 += __shfl_xor(a4, 4); a5 += __shfl_xor(a5, 4);
    a6 += __shfl_xor(a6, 4); a7 += __shfl_xor(a7, 4);
    a0 += __shfl_xor(a0, 8); a1 += __shfl_xor(a1, 8);
    a2 += __shfl_xor(a2, 8); a3 += __shfl_xor(a3, 8);
    a4 += __shfl_xor(a4, 8); a5 += __shfl_xor(a5, 8);
    a6 += __shfl_xor(a6, 8); a7 += __shfl_xor(a7, 8);
    uint4 su = ((const uint4*)(hs + (size_t)wid * 16))[half];   // self term
    a0 += bflo(su.x); a1 += bfhi(su.x);
    a2 += bflo(su.y); a3 += bfhi(su.y);
    a4 += bflo(su.z); a5 += bfhi(su.z);
    a6 += bflo(su.w); a7 += bfhi(su.w);
    float di = dinv[wid];
    float4 bA = ((const float4*)b1)[half * 2];
    float4 bB = ((const float4*)b1)[half * 2 + 1];
    float v0 = fmaxf(fmaf(di, a0, bA.x), 0.f);
    float v1 = fmaxf(fmaf(di, a1, bA.y), 0.f);
    float v2 = fmaxf(fmaf(di, a2, bA.z), 0.f);
    float v3 = fmaxf(fmaf(di, a3, bA.w), 0.f);
    float v4 = fmaxf(fmaf(di, a4, bB.x), 0.f);
    float v5 = fmaxf(fmaf(di, a5, bB.y), 0.f);
    float v6 = fmaxf(fmaf(di, a6, bB.z), 0.f);
    float v7 = fmaxf(fmaf(di, a7, bB.w), 0.f);
    const float4* w4 = (const float4*)W2 + half * 4;   // rows half*8..+7
    float4 q0 = w4[0], q1 = w4[1], q2 = w4[2], q3 = w4[3];
    float p0 = v0*q0.x + v1*q0.z + v2*q1.x + v3*q1.z
             + v4*q2.x + v5*q2.z + v6*q3.x + v7*q3.z;
    float p1 = v0*q0.y + v1*q0.w + v2*q1.y + v3*q1.w
             + v4*q2.y + v5*q2.w + v6*q3.y + v7*q3.w;
    p0 += __shfl_xor(p0, 1); p1 += __shfl_xor(p1, 1);  // sum the two halves
    if (l == 0)
        *(float2*)(h2s + (size_t)wid * 2) = make_float2(p0 * di, p1 * di);
}

// ---------------- layer-2 gather -> out (4 nodes/wave, 16 lanes/node) --------
__global__ __launch_bounds__(256) void k_agg2(const int* __restrict__ rp,
                                              const int* __restrict__ csr,
                                              const float* __restrict__ h2s,
                                              const float* __restrict__ dinv,
                                              const float* __restrict__ b2,
                                              float* __restrict__ out, int N) {
    int lane = threadIdx.x & 63;
    int wid = blockIdx.x * 16 + (threadIdx.x >> 6) * 4 + (lane >> 4);
    if (wid >= N) return;
    int l = lane & 15;
    int beg = rp[wid], end = rp[wid + 1];
    float a0 = 0.f, a1 = 0.f;
    for (int j = beg + l; j < end; j += 16) {
        int s = csr[j];
        float2 v = *(const float2*)(h2s + (size_t)s * 2);
        a0 += v.x; a1 += v.y;
    }
    a0 += __shfl_xor(a0, 1); a1 += __shfl_xor(a1, 1);
    a0 += __shfl_xor(a0, 2); a1 += __shfl_xor(a1, 2);
    a0 += __shfl_xor(a0, 4); a1 += __shfl_xor(a1, 4);
    a0 += __shfl_xor(a0, 8); a1 += __shfl_xor(a1, 8);
    if (l == 0) {
        float di = dinv[wid];
        float2 sv = *(const float2*)(h2s + (size_t)wid * 2);
        *(float2*)(out + (size_t)wid * 2) =
            make_float2(fmaf(di, a0 + sv.x, b2[0]), fmaf(di, a1 + sv.y, b2[1]));
    }
}

extern "C" void kernel_launch(void* const* d_in, const int* in_sizes, int n_in,
                              void* d_out, int out_size, void* d_ws, size_t ws_size,
                              hipStream_t stream) {
    const float* x  = (const float*)d_in[0];
    const int*   ei = (const int*)d_in[1];
    const float* W1 = (const float*)d_in[2];
    const float* b1 = (const float*)d_in[3];
    const float* W2 = (const float*)d_in[4];
    const float* b2 = (const float*)d_in[5];
    float* out = (float*)d_out;

    const int N = in_sizes[0] / 128;      // 100000
    const int E = in_sizes[1] / 2;        // 3200000
    const int NBUK = (N + 255) / 256;     // 391 (<= 512)
    const int NPB  = (E + EPB - 1) / EPB; // 391 (scatter blocks)
    const int NXW  = (N * 4 + 511) / 512; // 782 (xw1 blocks)

    char* ws = (char*)d_ws;
    size_t off = 0;
    auto alloc = [&](size_t bytes) {
        void* p = ws + off;
        off = (off + bytes + 255) & ~(size_t)255;
        return p;
    };
    u32*   part  = (u32*)alloc((size_t)NBUK * RCAP * 4); // strided regions
    u32*   csr   = (u32*)alloc((size_t)E * 4);           // dense sorted
    int*   rp    = (int*)alloc((size_t)(N + 1) * 4);
    float* dinv  = (float*)alloc((size_t)N * 4);
    float* hraw  = (float*)alloc((size_t)N * 16 * 4);    // f32 x@W1, no dinv
    u16*   hs    = (u16*)alloc((size_t)N * 16 * 2);      // bf16 scaled
    float* h2s   = (float*)alloc((size_t)N * 2 * 4);
    int*   gcur  = (int*)alloc((size_t)NBUK * 4);        // pure counts

    hipMemsetAsync(gcur, 0, (size_t)NBUK * 4, stream);   // replaces k_binit
    k_fat    <<<dim3(NPB + NXW),  dim3(512), 0, stream>>>(ei, gcur, part, x, W1, hraw, E, NBUK, NPB, N);
    k_fillB  <<<dim3(NBUK),       dim3(512), 0, stream>>>(part, gcur, csr, rp, dinv, hraw, hs, N, E, NBUK);
    k_agg1h2 <<<dim3((N + 15) / 16), dim3(256), 0, stream>>>(rp, (const int*)csr, hs, dinv, W2, b1, h2s, N);
    k_agg2   <<<dim3((N + 15) / 16), dim3(256), 0, stream>>>(rp, (const int*)csr, h2s, dinv, b2, out, N);
}

// Round 15
// 176.756 us; speedup vs baseline: 1.1422x; 1.0288x over previous
//
#include <hip/hip_runtime.h>

// GCN 2-layer forward, N=100000, E=3200000, 128->16->2.
// Session-2 round-14 (prev 181.8us; r11 revert confirmed; memsetAsync swap
// cost +2.6 vs k_binit -- rocclr fillBuffer dispatch is HEAVIER than a
// 1-block kernel. LESSON: don't assume runtime memset is free).
// This round: restore k_binit (gcur stays pure-count) + ONE change:
// hierarchical shfl scans. fat-scatter (18 barriers) and fillB (~34
// barriers over 2 scans) are latency-bound (r12: VALU 12%, Occ 40%,
// HBM 25%); wave-shfl scan (64-lane shfl_up -> 8 wave sums -> offset)
// does each scan in 2 barriers. fillB's 512-wide scan only feeds this
// block's base_w -> bs[512] eliminated, one-int broadcast instead.
// Integer-identical results; bit-identical output.
// Validated and kept: fat scatter||xw1 fusion (-9.1us), deferred dinv
// scale in fillB tail, fixed-stride regions (EPB 8192), register-staged
// scatter, uint4 fillB passes, 4-nodes/wave agg.
// LESSONS: hot-address global atomicAdd serializes; LDS-atomic agg 8x
// worse than sorted gather; many nodes/wave + shallow trees (r8); measure
// Occupancy before tuning for it (r11/r12); data-layout contiguity beats
// divergence fixes (r11 perm).
// Algebra: hs = (x@W1)*dinv;
//   h1[d]  = relu(dinv[d]*(sum_nbr hs + hs[d]) + b1), W2 fused -> h2s
//   out[d] = dinv[d]*(sum_nbr h2s + h2s[d]) + b2

#define EPB  8192    // edges per partition block
#define RCAP 12288   // per-bucket region capacity (mean 8192, sigma~90)
#define CAP  16384   // LDS slots per bucket in k_fillB

typedef unsigned int u32;
typedef unsigned short u16;

__device__ __forceinline__ float bflo(u32 u) { return __uint_as_float(u << 16); }
__device__ __forceinline__ float bfhi(u32 u) { return __uint_as_float(u & 0xffff0000u); }
__device__ __forceinline__ u32 pack_bf2(float a, float b) {   // RNE
    u32 ua = __float_as_uint(a); ua = (ua + 0x7fffu + ((ua >> 16) & 1u)) >> 16;
    u32 ub = __float_as_uint(b); ub = (ub + 0x7fffu + ((ub >> 16) & 1u)) >> 16;
    return ua | (ub << 16);
}

// 64-lane inclusive scan (no barriers)
__device__ __forceinline__ int wscan(int v) {
    int lane = threadIdx.x & 63;
    #pragma unroll
    for (int o = 1; o < 64; o <<= 1) {
        int t = __shfl_up(v, o);
        if (lane >= o) v += t;
    }
    return v;
}
// inclusive block scan over 512 threads; ws = 8-int LDS scratch; 2 barriers.
// Trailing barrier guarantees ws reads done before caller reuses the scratch.
__device__ __forceinline__ int bscan512(int v, int* ws) {
    int lane = threadIdx.x & 63, w = threadIdx.x >> 6;
    int s = wscan(v);
    if (lane == 63) ws[w] = s;
    __syncthreads();
    int off = 0;
    #pragma unroll
    for (int i = 0; i < 7; ++i)
        if (i < w) off += ws[i];
    __syncthreads();
    return s + off;
}

// ---------------- zero bucket counters ----------------
__global__ __launch_bounds__(512) void k_binit(int* __restrict__ gcur, int NBUK) {
    int t = threadIdx.x;
    if (t < NBUK) gcur[t] = 0;
}

// ---------------- FAT: partition (blocks < NSCAT) || hraw = x@W1 (rest) -----
__global__ __launch_bounds__(512) void k_fat(const int* __restrict__ ei,
                                             int* __restrict__ gcur,
                                             u32* __restrict__ part,
                                             const float* __restrict__ x,
                                             const float* __restrict__ W1,
                                             float* __restrict__ hraw,
                                             int E, int NBUK, int NSCAT, int N) {
    __shared__ union {
        struct { int hist[512]; int rbase[512]; u32 buf[EPB]; u16 bkt[EPB]; } s;
        float w[4 * 516];   // xw1: section q = W1 rows 32q..32q+31; +4 pad
    } sm;
    int tid = threadIdx.x;
    if ((int)blockIdx.x < NSCAT) {
        // ---- scatter: count+scan+reserve+place, edges staged in registers --
        sm.s.hist[tid] = 0;
        __syncthreads();
        int base = blockIdx.x * EPB;
        int end = base + EPB; if (end > E) end = E;
        int cnt = end - base;
        int nv = cnt >> 2;
        const int4* s4p = (const int4*)(ei + base);
        const int4* d4p = (const int4*)(ei + E + base);
        int4 s4[4], d4[4];
        #pragma unroll
        for (int k = 0; k < 4; ++k) {
            int idx = tid + (k << 9);
            if (idx < nv) {
                s4[k] = s4p[idx];
                d4[k] = d4p[idx];
                atomicAdd(&sm.s.hist[d4[k].x >> 8], 1);
                atomicAdd(&sm.s.hist[d4[k].y >> 8], 1);
                atomicAdd(&sm.s.hist[d4[k].z >> 8], 1);
                atomicAdd(&sm.s.hist[d4[k].w >> 8], 1);
            }
        }
        for (int e = base + (nv << 2) + tid; e < end; e += 512)  // tail
            atomicAdd(&sm.s.hist[ei[E + e] >> 8], 1);
        __syncthreads();
        int v = sm.s.hist[tid];
        // shfl-based scan: 2 barriers (rbase[0..7] as scratch; trailing
        // barrier in bscan512 orders scratch reads before rbase writes below)
        int incl = bscan512(v, sm.s.rbase);
        int excl = incl - v;
        int rb = 0;
        if (tid < NBUK && v > 0)                                 // reserve run
            rb = tid * RCAP + atomicAdd(&gcur[tid], v);
        sm.s.rbase[tid] = rb - excl;
        sm.s.hist[tid] = excl;        // placement cursor (own slot only)
        __syncthreads();
        #pragma unroll
        for (int k = 0; k < 4; ++k) {
            int idx = tid + (k << 9);
            if (idx < nv) {
                int b, pos;
                b = d4[k].x >> 8; pos = atomicAdd(&sm.s.hist[b], 1);
                sm.s.buf[pos] = ((u32)(d4[k].x & 255) << 24) | (u32)s4[k].x; sm.s.bkt[pos] = (u16)b;
                b = d4[k].y >> 8; pos = atomicAdd(&sm.s.hist[b], 1);
                sm.s.buf[pos] = ((u32)(d4[k].y & 255) << 24) | (u32)s4[k].y; sm.s.bkt[pos] = (u16)b;
                b = d4[k].z >> 8; pos = atomicAdd(&sm.s.hist[b], 1);
                sm.s.buf[pos] = ((u32)(d4[k].z & 255) << 24) | (u32)s4[k].z; sm.s.bkt[pos] = (u16)b;
                b = d4[k].w >> 8; pos = atomicAdd(&sm.s.hist[b], 1);
                sm.s.buf[pos] = ((u32)(d4[k].w & 255) << 24) | (u32)s4[k].w; sm.s.bkt[pos] = (u16)b;
            }
        }
        for (int e = base + (nv << 2) + tid; e < end; e += 512) { // tail re-read
            int s = ei[e], d = ei[E + e];
            int b = d >> 8;
            int pos = atomicAdd(&sm.s.hist[b], 1);
            sm.s.buf[pos] = ((u32)(d & 255) << 24) | (u32)s;
            sm.s.bkt[pos] = (u16)b;
        }
        __syncthreads();
        for (int j = tid; j < cnt; j += 512)
            part[sm.s.rbase[sm.s.bkt[j]] + j] = sm.s.buf[j];     // ~coalesced
    } else {
        // ---- xw1_raw: hraw[n][16] = x[n]@W1 (f32, no dinv), K-split x4 -----
        for (int t = tid; t < 2048; t += 512)
            sm.w[(t >> 9) * 516 + (t & 511)] = W1[t];
        __syncthreads();
        int t = ((int)blockIdx.x - NSCAT) * 512 + tid;
        int n = t >> 2, q = t & 3;
        if (n >= N) return;
        const float4* xr = (const float4*)(x + (size_t)n * 128 + q * 32);  // 8 f4
        const float* ws = sm.w + q * 516;
        float acc[16];
        #pragma unroll
        for (int c = 0; c < 16; ++c) acc[c] = 0.f;
        #pragma unroll
        for (int i = 0; i < 8; ++i) {
            float4 u = xr[i];
            const float4* wf = (const float4*)(ws + i * 64);  // rows 4i..4i+3
            #pragma unroll
            for (int c4 = 0; c4 < 4; ++c4) {
                float4 wa = wf[c4];
                float4 wb = wf[4 + c4];
                float4 wc = wf[8 + c4];
                float4 wd = wf[12 + c4];
                int c = c4 * 4;
                acc[c+0] = fmaf(u.x, wa.x, acc[c+0]); acc[c+1] = fmaf(u.x, wa.y, acc[c+1]);
                acc[c+2] = fmaf(u.x, wa.z, acc[c+2]); acc[c+3] = fmaf(u.x, wa.w, acc[c+3]);
                acc[c+0] = fmaf(u.y, wb.x, acc[c+0]); acc[c+1] = fmaf(u.y, wb.y, acc[c+1]);
                acc[c+2] = fmaf(u.y, wb.z, acc[c+2]); acc[c+3] = fmaf(u.y, wb.w, acc[c+3]);
                acc[c+0] = fmaf(u.z, wc.x, acc[c+0]); acc[c+1] = fmaf(u.z, wc.y, acc[c+1]);
                acc[c+2] = fmaf(u.z, wc.z, acc[c+2]); acc[c+3] = fmaf(u.z, wc.w, acc[c+3]);
                acc[c+0] = fmaf(u.w, wd.x, acc[c+0]); acc[c+1] = fmaf(u.w, wd.y, acc[c+1]);
                acc[c+2] = fmaf(u.w, wd.z, acc[c+2]); acc[c+3] = fmaf(u.w, wd.w, acc[c+3]);
            }
        }
        #pragma unroll
        for (int c = 0; c < 16; ++c) {
            acc[c] += __shfl_xor(acc[c], 1);
            acc[c] += __shfl_xor(acc[c], 2);
        }
        ((float4*)(hraw + (size_t)n * 16))[q] =
            make_float4(acc[4*q+0], acc[4*q+1], acc[4*q+2], acc[4*q+3]);
    }
}

// ---------------- per-bucket sort by dst; region -> dense csr ---------------
// shfl-scan base_w broadcast (bs[512] gone); uint4 passes; hs-scale tail.
__global__ __launch_bounds__(512) void k_fillB(const u32* __restrict__ part,
                                               const int* __restrict__ gcur,
                                               u32* __restrict__ csr,
                                               int* __restrict__ rp,
                                               float* __restrict__ dinv,
                                               const float* __restrict__ hraw,
                                               u16* __restrict__ hs,
                                               int N, int E, int NBUK) {
    __shared__ int hist[256];    // counts -> placement cursors
    __shared__ int ws[8];        // scan scratch
    __shared__ int sbw[1];       // base_w broadcast
    __shared__ float dstash[256];
    __shared__ u32 srcbuf[CAP];
    int b = blockIdx.x, tid = threadIdx.x;
    if (b == 0 && tid == 0) rp[N] = E;
    int vb = (tid < NBUK) ? gcur[tid] : 0;         // bucket counts
    if (tid < 256) hist[tid] = 0;
    int inclb = bscan512(vb, ws);                  // 2 barriers
    if (tid == b) sbw[0] = inclb - vb;             // exclusive prefix
    __syncthreads();
    int base_w = sbw[0];                           // dense write base
    int cnt = gcur[b];
    int base_r = b * RCAP;                         // region read base
    int nv = cnt >> 2;
    const uint4* p4 = (const uint4*)(part + base_r);
    for (int t = tid; t < nv; t += 512) {
        uint4 pv = p4[t];
        atomicAdd(&hist[pv.x >> 24], 1);
        atomicAdd(&hist[pv.y >> 24], 1);
        atomicAdd(&hist[pv.z >> 24], 1);
        atomicAdd(&hist[pv.w >> 24], 1);
    }
    for (int j = (nv << 2) + tid; j < cnt; j += 512)
        atomicAdd(&hist[part[base_r + j] >> 24], 1);
    __syncthreads();
    int v = (tid < 256) ? hist[tid] : 0;
    int incl = bscan512(v, ws);                    // 2 barriers
    int excl = incl - v;
    if (tid < 256) hist[tid] = excl;               // placement cursors
    __syncthreads();
    for (int t = tid; t < nv; t += 512) {
        uint4 pv = p4[t];
        int pos;
        pos = atomicAdd(&hist[pv.x >> 24], 1);
        if (pos < CAP) srcbuf[pos] = pv.x & 0xFFFFFFu;
        pos = atomicAdd(&hist[pv.y >> 24], 1);
        if (pos < CAP) srcbuf[pos] = pv.y & 0xFFFFFFu;
        pos = atomicAdd(&hist[pv.z >> 24], 1);
        if (pos < CAP) srcbuf[pos] = pv.z & 0xFFFFFFu;
        pos = atomicAdd(&hist[pv.w >> 24], 1);
        if (pos < CAP) srcbuf[pos] = pv.w & 0xFFFFFFu;
    }
    for (int j = (nv << 2) + tid; j < cnt; j += 512) {
        u32 pv = part[base_r + j];
        int pos = atomicAdd(&hist[pv >> 24], 1);
        if (pos < CAP) srcbuf[pos] = pv & 0xFFFFFFu;
    }
    __syncthreads();
    for (int j = tid; j < cnt; j += 512)
        csr[base_w + j] = srcbuf[j];       // coalesced dense write
    int d = b * 256 + tid;
    if (tid < 256 && d < N) {
        rp[d] = base_w + excl;
        float dval = rsqrtf((float)(v + 1));   // +1 self loop
        dinv[d] = dval;
        dstash[tid] = dval;
    }
    __syncthreads();
    // ---- hs[dn] = bf16(hraw[dn] * dinv[dn]); 2 threads/node, 16B halves ----
    int dn = b * 256 + (tid >> 1);
    if (dn < N) {
        float di = dstash[tid >> 1];
        int h = tid & 1;
        const float4* hr = (const float4*)(hraw + (size_t)dn * 16);
        float4 A = hr[h * 2], B = hr[h * 2 + 1];
        uint4 o;
        o.x = pack_bf2(A.x * di, A.y * di);
        o.y = pack_bf2(A.z * di, A.w * di);
        o.z = pack_bf2(B.x * di, B.y * di);
        o.w = pack_bf2(B.z * di, B.w * di);
        ((uint4*)(hs + (size_t)dn * 16))[h] = o;
    }
}

// ---------------- fused layer-1 gather + ReLU + W2 projection ----------------
// 4 nodes/wave; 16 lanes/node = 2 halves (16B uint4 each) x 8 edge groups.
__global__ __launch_bounds__(256) void k_agg1h2(const int* __restrict__ rp,
                                                const int* __restrict__ csr,
                                                const u16* __restrict__ hs,
                                                const float* __restrict__ dinv,
                                                const float* __restrict__ W2,
                                                const float* __restrict__ b1,
                                                float* __restrict__ h2s, int N) {
    int lane = threadIdx.x & 63;
    int wid = blockIdx.x * 16 + (threadIdx.x >> 6) * 4 + (lane >> 4);
    if (wid >= N) return;
    int l = lane & 15;
    int half = l & 1, g = l >> 1;                  // 16B half, edge group
    int beg = rp[wid], end = rp[wid + 1];
    float a0 = 0.f, a1 = 0.f, a2 = 0.f, a3 = 0.f;
    float a4 = 0.f, a5 = 0.f, a6 = 0.f, a7 = 0.f;
    for (int j = beg + g; j < end; j += 8) {
        int s = csr[j];
        uint4 u = ((const uint4*)(hs + (size_t)s * 16))[half];
        a0 += bflo(u.x); a1 += bfhi(u.x);
        a2 += bflo(u.y); a3 += bfhi(u.y);
        a4 += bflo(u.z); a5 += bfhi(u.z);
        a6 += bflo(u.w); a7 += bfhi(u.w);
    }
    a0 += __shfl_xor(a0, 2); a1 += __shfl_xor(a1, 2);
    a2 += __shfl_xor(a2, 2); a3 += __shfl_xor(a3, 2);
    a4 += __shfl_xor(a4, 2); a5 += __shfl_xor(a5, 2);
    a6 += __shfl_xor(a6, 2); a7 += __shfl_xor(a7, 2);
    a0 += __shfl_xor(a0, 4); a1 += __shfl_xor(a1, 4);
    a2 += __shfl_xor(a2, 4); a3 += __shfl_xor(a3, 4);
    a4 += __shfl_xor(a4, 4); a5 += __shfl_xor(a5, 4);
    a6 += __shfl_xor(a6, 4); a7 += __shfl_xor(a7, 4);
    a0 += __shfl_xor(a0, 8); a1 += __shfl_xor(a1, 8);
    a2 += __shfl_xor(a2, 8); a3 += __shfl_xor(a3, 8);
    a4 += __shfl_xor(a4, 8); a5 += __shfl_xor(a5, 8);
    a6 += __shfl_xor(a6, 8); a7 += __shfl_xor(a7, 8);
    uint4 su = ((const uint4*)(hs + (size_t)wid * 16))[half];   // self term
    a0 += bflo(su.x); a1 += bfhi(su.x);
    a2 += bflo(su.y); a3 += bfhi(su.y);
    a4 += bflo(su.z); a5 += bfhi(su.z);
    a6 += bflo(su.w); a7 += bfhi(su.w);
    float di = dinv[wid];
    float4 bA = ((const float4*)b1)[half * 2];
    float4 bB = ((const float4*)b1)[half * 2 + 1];
    float v0 = fmaxf(fmaf(di, a0, bA.x), 0.f);
    float v1 = fmaxf(fmaf(di, a1, bA.y), 0.f);
    float v2 = fmaxf(fmaf(di, a2, bA.z), 0.f);
    float v3 = fmaxf(fmaf(di, a3, bA.w), 0.f);
    float v4 = fmaxf(fmaf(di, a4, bB.x), 0.f);
    float v5 = fmaxf(fmaf(di, a5, bB.y), 0.f);
    float v6 = fmaxf(fmaf(di, a6, bB.z), 0.f);
    float v7 = fmaxf(fmaf(di, a7, bB.w), 0.f);
    const float4* w4 = (const float4*)W2 + half * 4;   // rows half*8..+7
    float4 q0 = w4[0], q1 = w4[1], q2 = w4[2], q3 = w4[3];
    float p0 = v0*q0.x + v1*q0.z + v2*q1.x + v3*q1.z
             + v4*q2.x + v5*q2.z + v6*q3.x + v7*q3.z;
    float p1 = v0*q0.y + v1*q0.w + v2*q1.y + v3*q1.w
             + v4*q2.y + v5*q2.w + v6*q3.y + v7*q3.w;
    p0 += __shfl_xor(p0, 1); p1 += __shfl_xor(p1, 1);  // sum the two halves
    if (l == 0)
        *(float2*)(h2s + (size_t)wid * 2) = make_float2(p0 * di, p1 * di);
}

// ---------------- layer-2 gather -> out (4 nodes/wave, 16 lanes/node) --------
__global__ __launch_bounds__(256) void k_agg2(const int* __restrict__ rp,
                                              const int* __restrict__ csr,
                                              const float* __restrict__ h2s,
                                              const float* __restrict__ dinv,
                                              const float* __restrict__ b2,
                                              float* __restrict__ out, int N) {
    int lane = threadIdx.x & 63;
    int wid = blockIdx.x * 16 + (threadIdx.x >> 6) * 4 + (lane >> 4);
    if (wid >= N) return;
    int l = lane & 15;
    int beg = rp[wid], end = rp[wid + 1];
    float a0 = 0.f, a1 = 0.f;
    for (int j = beg + l; j < end; j += 16) {
        int s = csr[j];
        float2 v = *(const float2*)(h2s + (size_t)s * 2);
        a0 += v.x; a1 += v.y;
    }
    a0 += __shfl_xor(a0, 1); a1 += __shfl_xor(a1, 1);
    a0 += __shfl_xor(a0, 2); a1 += __shfl_xor(a1, 2);
    a0 += __shfl_xor(a0, 4); a1 += __shfl_xor(a1, 4);
    a0 += __shfl_xor(a0, 8); a1 += __shfl_xor(a1, 8);
    if (l == 0) {
        float di = dinv[wid];
        float2 sv = *(const float2*)(h2s + (size_t)wid * 2);
        *(float2*)(out + (size_t)wid * 2) =
            make_float2(fmaf(di, a0 + sv.x, b2[0]), fmaf(di, a1 + sv.y, b2[1]));
    }
}

extern "C" void kernel_launch(void* const* d_in, const int* in_sizes, int n_in,
                              void* d_out, int out_size, void* d_ws, size_t ws_size,
                              hipStream_t stream) {
    const float* x  = (const float*)d_in[0];
    const int*   ei = (const int*)d_in[1];
    const float* W1 = (const float*)d_in[2];
    const float* b1 = (const float*)d_in[3];
    const float* W2 = (const float*)d_in[4];
    const float* b2 = (const float*)d_in[5];
    float* out = (float*)d_out;

    const int N = in_sizes[0] / 128;      // 100000
    const int E = in_sizes[1] / 2;        // 3200000
    const int NBUK = (N + 255) / 256;     // 391 (<= 512)
    const int NPB  = (E + EPB - 1) / EPB; // 391 (scatter blocks)
    const int NXW  = (N * 4 + 511) / 512; // 782 (xw1 blocks)

    char* ws = (char*)d_ws;
    size_t off = 0;
    auto alloc = [&](size_t bytes) {
        void* p = ws + off;
        off = (off + bytes + 255) & ~(size_t)255;
        return p;
    };
    u32*   part  = (u32*)alloc((size_t)NBUK * RCAP * 4); // strided regions
    u32*   csr   = (u32*)alloc((size_t)E * 4);           // dense sorted
    int*   rp    = (int*)alloc((size_t)(N + 1) * 4);
    float* dinv  = (float*)alloc((size_t)N * 4);
    float* hraw  = (float*)alloc((size_t)N * 16 * 4);    // f32 x@W1, no dinv
    u16*   hs    = (u16*)alloc((size_t)N * 16 * 2);      // bf16 scaled
    float* h2s   = (float*)alloc((size_t)N * 2 * 4);
    int*   gcur  = (int*)alloc((size_t)NBUK * 4);        // pure counts

    k_binit  <<<dim3(1),          dim3(512), 0, stream>>>(gcur, NBUK);
    k_fat    <<<dim3(NPB + NXW),  dim3(512), 0, stream>>>(ei, gcur, part, x, W1, hraw, E, NBUK, NPB, N);
    k_fillB  <<<dim3(NBUK),       dim3(512), 0, stream>>>(part, gcur, csr, rp, dinv, hraw, hs, N, E, NBUK);
    k_agg1h2 <<<dim3((N + 15) / 16), dim3(256), 0, stream>>>(rp, (const int*)csr, hs, dinv, W2, b1, h2s, N);
    k_agg2   <<<dim3((N + 15) / 16), dim3(256), 0, stream>>>(rp, (const int*)csr, h2s, dinv, b2, out, N);
}